// Round 1
// baseline (486.452 us; speedup 1.0000x reference)
//
#include <hip/hip_runtime.h>
#include <math.h>

#define B_ 8
#define N_ 2048
static constexpr int BN = B_ * N_;
static constexpr int THREADS = 256;
static constexpr int WPC = 64;                     // workgroups per cloud-direction
static constexpr int ROWS_PER_WG = N_ / WPC;       // 32
static constexpr int RG = 8;                       // row groups (4 rows each) per WG
static constexpr int NSTRIPE = THREADS / RG;       // 32 j-stripes
static constexpr int JPER = N_ / NSTRIPE;          // 64 j's per stripe

#if __has_builtin(__builtin_amdgcn_exp2f)
#define FEXP2(x) __builtin_amdgcn_exp2f(x)
#else
#define FEXP2(x) exp2f(x)
#endif

// ws layout (floats): remL[B][N] | remR[B][N] | ratioL[10][B][N] | ratioR[10][B][N]
// MODE 0: bootstrap row pass (level 0, remL=remR=1): t1 = sum_j W, ratioL0 = 1/(1e-9+t1)
// MODE 1: col pass (level l): t2_j = sum_i W*ratioL_l[i]; ratioR_l, remR update
// MODE 2: fused C(l)+A(l+1) row pass: t3 = sum_j W_l*ratioR_l[j]; t1' = sum_j W_{l+1}*remR[j]
template<int MODE>
__global__ __launch_bounds__(THREADS)
void pass_kernel(const float* __restrict__ xyz1, const float* __restrict__ xyz2,
                 float* __restrict__ ws, float* __restrict__ outCost,
                 float cA, float cB, int lvl)
{
    __shared__ float4 pts[N_];
    __shared__ float rem2[(MODE==2) ? N_ : 1];
    __shared__ float red1[4][RG][4];
    __shared__ float red2[4][RG][4];

    float* remL = ws;
    float* remR = ws + BN;
    float* ratL = ws + 2*BN;
    float* ratR = ws + 12*BN;

    const int wg = blockIdx.x;
    const int b = wg / WPC;
    const int wloc = wg - b*WPC;
    const int t = threadIdx.x;

    if (MODE==0 && wg==0 && t < B_) outCost[t] = 0.0f;   // zero cost accumulators

    const float* colxyz = (MODE==1) ? xyz1 : xyz2;   // cloud staged in LDS
    const float* rowxyz = (MODE==1) ? xyz2 : xyz1;   // cloud owned in registers
    const float* wvec   = (MODE==1) ? (ratL + (size_t)lvl*BN)
                        : (MODE==2) ? (ratR + (size_t)lvl*BN) : nullptr;

    for (int j = t; j < N_; j += THREADS) {
        const float* p = colxyz + (size_t)(b*N_ + j)*3;
        float w = (MODE==0) ? 0.0f : wvec[b*N_ + j];
        pts[j] = make_float4(p[0], p[1], p[2], w);
        if (MODE==2) rem2[j] = remR[b*N_ + j];
    }

    const int rg = t & (RG-1);
    const int stripe = t >> 3;                  // 0..31
    const int rowbase = wloc*ROWS_PER_WG + rg*4;
    float rx[4], ry[4], rz[4];
    #pragma unroll
    for (int r = 0; r < 4; ++r) {
        const float* q = rowxyz + (size_t)(b*N_ + rowbase + r)*3;
        rx[r] = q[0]; ry[r] = q[1]; rz[r] = q[2];
    }
    __syncthreads();

    float acc1[4] = {0.f,0.f,0.f,0.f};
    float acc2[4] = {0.f,0.f,0.f,0.f};
    const int jbase = stripe * JPER;
    const int jrot  = 2*stripe;                 // stagger -> 2-way (free) LDS conflicts
    for (int jj = 0; jj < JPER; ++jj) {
        const int j = jbase + ((jj + jrot) & (JPER-1));
        const float4 p = pts[j];
        float rr = 0.f;
        if (MODE==2) rr = rem2[j];
        #pragma unroll
        for (int r = 0; r < 4; ++r) {
            float dx = rx[r]-p.x, dy = ry[r]-p.y, dz = rz[r]-p.z;
            float sqd = fmaf(dx,dx, fmaf(dy,dy, dz*dz));
            float w1 = FEXP2(cA*sqd);
            if (MODE==0) acc1[r] += w1;
            else         acc1[r] = fmaf(w1, p.w, acc1[r]);
            if (MODE==2) {
                float w2 = FEXP2(cB*sqd);
                acc2[r] = fmaf(w2, rr, acc2[r]);
            }
        }
    }

    // reduce over stripes: within-wave (lane bits 3..5 are stripe bits), then cross-wave
    #pragma unroll
    for (int r = 0; r < 4; ++r) {
        float v = acc1[r];
        v += __shfl_xor(v, 8); v += __shfl_xor(v, 16); v += __shfl_xor(v, 32);
        acc1[r] = v;
        if (MODE==2) {
            float u = acc2[r];
            u += __shfl_xor(u, 8); u += __shfl_xor(u, 16); u += __shfl_xor(u, 32);
            acc2[r] = u;
        }
    }
    const int wave = t >> 6, lane = t & 63;
    if (lane < RG) {
        #pragma unroll
        for (int r = 0; r < 4; ++r) {
            red1[wave][lane][r] = acc1[r];
            if (MODE==2) red2[wave][lane][r] = acc2[r];
        }
    }
    __syncthreads();
    if (t < ROWS_PER_WG) {
        const int rgf = t >> 2, ri = t & 3;
        float s1 = red1[0][rgf][ri]+red1[1][rgf][ri]+red1[2][rgf][ri]+red1[3][rgf][ri];
        const int gi = b*N_ + wloc*ROWS_PER_WG + rgf*4 + ri;
        if (MODE==0) {
            ratL[gi] = 1.0f / (1e-9f + s1);     // remL=1
            remL[gi] = 1.0f;
            remR[gi] = 1.0f;                    // n==m: rows double as col init
        } else if (MODE==1) {
            float rr  = remR[gi];
            float rat = rr / (1e-9f + s1);
            ratR[(size_t)lvl*BN + gi] = rat;
            remR[gi] = fmaxf(0.0f, rr - rat*s1);
        } else {
            float s2 = red2[0][rgf][ri]+red2[1][rgf][ri]+red2[2][rgf][ri]+red2[3][rgf][ri];
            float rl  = remL[gi];
            float rlo = ratL[(size_t)lvl*BN + gi];
            float nl  = fmaxf(0.0f, rl - rlo*s1);
            remL[gi] = nl;
            ratL[(size_t)(lvl+1)*BN + gi] = nl / (1e-9f + s2);
        }
    }
}

// match_ij = sum_l W_l * ratioL_l[i] * ratioR_l[j]; out[b][j][i] = match_ij (transposed)
// cost_b = sum_ij match_ij * sqrt(sqd_ij)
static constexpr int MT  = 256;
static constexpr int JCH = 256;

__global__ __launch_bounds__(MT)
void match_kernel(const float* __restrict__ xyz1, const float* __restrict__ xyz2,
                  const float* __restrict__ ws, float* __restrict__ out, float c0)
{
    __shared__ float4 pts[JCH];
    __shared__ float rr[10][JCH];
    __shared__ float cred[MT/64];

    const float* ratL = ws + 2*BN;
    const float* ratR = ws + 12*BN;
    float* outCost  = out;
    float* outMatch = out + B_;

    const int wg = blockIdx.x;       // b*64 + jc*8 + ic
    const int b  = wg >> 6;
    const int jc = (wg >> 3) & 7;
    const int ic = wg & 7;
    const int t  = threadIdx.x;

    const int i = ic*MT + t;
    const float* q = xyz1 + (size_t)(b*N_ + i)*3;
    const float x1 = q[0], y1 = q[1], z1 = q[2];
    float RL[10];
    #pragma unroll
    for (int l = 0; l < 10; ++l) RL[l] = ratL[(size_t)l*BN + b*N_ + i];

    {   // stage this j-chunk: points + 10 ratioR vectors
        const int gj = jc*JCH + t;
        const float* p = xyz2 + (size_t)(b*N_ + gj)*3;
        pts[t] = make_float4(p[0], p[1], p[2], 0.f);
        #pragma unroll
        for (int l = 0; l < 10; ++l) rr[l][t] = ratR[(size_t)l*BN + b*N_ + gj];
    }
    __syncthreads();

    float cost = 0.f;
    const size_t obase = (size_t)b*N_*N_ + (size_t)(jc*JCH)*N_ + (size_t)(ic*MT) + t;
    for (int jj = 0; jj < JCH; ++jj) {
        const float4 p = pts[jj];
        float dx = x1-p.x, dy = y1-p.y, dz = z1-p.z;
        float sqd = fmaf(dx,dx, fmaf(dy,dy, dz*dz));
        float m = 0.f;
        float arg = c0*sqd;                     // c_l = c_0 / 4^l exactly (l<9)
        #pragma unroll
        for (int l = 0; l < 9; ++l) {
            float w = FEXP2(arg);
            m = fmaf(w * RL[l], rr[l][jj], m);
            arg *= 0.25f;
        }
        m = fmaf(RL[9], rr[9][jj], m);          // level 9: W = 1
        outMatch[obase + (size_t)jj*N_] = m;
        cost = fmaf(m, sqrtf(sqd), cost);
    }

    // reduce cost: wave butterfly -> LDS -> one atomic per WG
    #pragma unroll
    for (int s = 1; s < 64; s <<= 1) cost += __shfl_xor(cost, s);
    const int wave = t >> 6, lane = t & 63;
    if (lane == 0) cred[wave] = cost;
    __syncthreads();
    if (t == 0) {
        float v = cred[0]+cred[1]+cred[2]+cred[3];
        atomicAdd(outCost + b, v);
    }
}

extern "C" void kernel_launch(void* const* d_in, const int* in_sizes, int n_in,
                              void* d_out, int out_size, void* d_ws, size_t ws_size,
                              hipStream_t stream) {
    const float* xyz1 = (const float*)d_in[0];
    const float* xyz2 = (const float*)d_in[1];
    float* out = (float*)d_out;
    float* ws  = (float*)d_ws;

    const double L2E = 1.4426950408889634;
    float c[10];
    for (int l = 0; l < 9; ++l) c[l] = (float)(-pow(4.0, 7 - l) * L2E);
    c[9] = 0.0f;

    dim3 grid(B_*WPC), blk(THREADS);
    // bootstrap: level 0 row pass (also inits remL/remR/cost)
    pass_kernel<0><<<grid, blk, 0, stream>>>(xyz1, xyz2, ws, out, c[0], 0.f, 0);
    for (int l = 0; l < 10; ++l) {
        pass_kernel<1><<<grid, blk, 0, stream>>>(xyz1, xyz2, ws, out, c[l], 0.f, l);
        if (l < 9)
            pass_kernel<2><<<grid, blk, 0, stream>>>(xyz1, xyz2, ws, out, c[l], c[l+1], l);
    }
    match_kernel<<<dim3(B_*64), dim3(MT), 0, stream>>>(xyz1, xyz2, ws, out, c[0]);
}

// Round 2
// 423.381 us; speedup vs baseline: 1.1490x; 1.1490x over previous
//
#include <hip/hip_runtime.h>
#include <math.h>

#define B_ 8
#define N_ 2048
static constexpr int BN = B_ * N_;
static constexpr int THREADS = 256;
static constexpr int WPC = 128;                 // workgroups per cloud-direction
static constexpr int ROWS_PER_WG = N_ / WPC;    // 16 (4 waves x 4 rows)

#if __has_builtin(__builtin_amdgcn_exp2f)
#define FEXP2(x) __builtin_amdgcn_exp2f(x)
#else
#define FEXP2(x) exp2f(x)
#endif

// ws layout (floats): remL[B][N] | remR[B][N] | ratioL[10][B][N] | ratioR[10][B][N]
//
// MODE 0: bootstrap row pass (level 0, remL=remR=1): t1 = sum_j W; ratioL0 = 1/(1e-9+t1)
// MODE 1: col pass (level l):  t2_j = sum_i W*ratioL_l[i]; ratioR_l, remR update
// MODE 2: fused C(l)+A(l+1) row pass: t3 = sum_j W_l*ratioR_l[j]; t1' = sum_j W_{l+1}*remR[j]
//         (W_{l+1} = W_l^{1/4} -> arg*0.25). CB0: l==8, c[l+1]==0 -> t1' = sum_j remR[j].
template<int MODE, bool CB0>
__global__ __launch_bounds__(THREADS, 4)
void pass_kernel(const float* __restrict__ xyz1, const float* __restrict__ xyz2,
                 float* __restrict__ ws, float* __restrict__ outCost,
                 float cA, float skipTh, int lvl)
{
    __shared__ float4 pts[N_];                      // x,y,z,w  (32 KB)
    __shared__ float rem2[(MODE==2) ? N_ : 1];      // mode2: +8 KB -> 40 KB total

    float* remL = ws;
    float* remR = ws + BN;
    float* ratL = ws + 2*BN;
    float* ratR = ws + 12*BN;

    const int wg   = blockIdx.x;
    const int b    = wg >> 7;           // WPC = 128
    const int wloc = wg & 127;
    const int t    = threadIdx.x;

    if (MODE==0 && wg==0 && t < B_) outCost[t] = 0.0f;   // zero cost accumulators

    const float* colxyz = (MODE==1) ? xyz1 : xyz2;   // cloud staged in LDS
    const float* rowxyz = (MODE==1) ? xyz2 : xyz1;   // cloud owned in registers
    const float* wvec   = (MODE==1) ? (ratL + (size_t)lvl*BN)
                        : (ratR + (size_t)lvl*BN);

    #pragma unroll
    for (int k = 0; k < N_/THREADS; ++k) {
        const int j = t + k*THREADS;
        const float* p = colxyz + (size_t)(b*N_ + j)*3;
        float w = 0.0f;
        if (MODE != 0) w = wvec[b*N_ + j];
        pts[j] = make_float4(p[0], p[1], p[2], w);
        if (MODE == 2) rem2[j] = remR[b*N_ + j];
    }

    const int wave = t >> 6, lane = t & 63;
    const int rowbase = wloc*ROWS_PER_WG + wave*4;
    float ax[4], ay[4], az[4], aq[4];
    #pragma unroll
    for (int r = 0; r < 4; ++r) {
        const float* q = rowxyz + (size_t)(b*N_ + rowbase + r)*3;
        const float qx = q[0], qy = q[1], qz = q[2];
        ax[r] = -2.0f*cA*qx; ay[r] = -2.0f*cA*qy; az[r] = -2.0f*cA*qz;
        aq[r] = cA * fmaf(qx,qx, fmaf(qy,qy, qz*qz));
    }
    __syncthreads();

    float acc1[4] = {0.f,0.f,0.f,0.f};
    float acc2[4] = {0.f,0.f,0.f,0.f};
    float sumRem = 0.f;

    #pragma unroll 4
    for (int jj = 0; jj < 32; ++jj) {
        const int j = (lane << 5) | ((jj + lane) & 31);   // rotate -> spread banks
        const float4 p = pts[j];
        if (MODE==2 && CB0) sumRem += rem2[j];
        const float cpp = cA * fmaf(p.x,p.x, fmaf(p.y,p.y, p.z*p.z));
        float a[4];
        #pragma unroll
        for (int r = 0; r < 4; ++r)
            a[r] = fmaf(ax[r],p.x, fmaf(ay[r],p.y, fmaf(az[r],p.z, cpp + aq[r])));
        const float amax = fmaxf(fmaxf(a[0],a[1]), fmaxf(a[2],a[3]));
        if (__any(amax >= skipTh)) {
            float rr = 0.f;
            if (MODE==2 && !CB0) rr = rem2[j];
            #pragma unroll
            for (int r = 0; r < 4; ++r) {
                const float w1 = FEXP2(a[r]);
                if (MODE==0) acc1[r] += w1;
                else         acc1[r] = fmaf(w1, p.w, acc1[r]);
                if (MODE==2 && !CB0)
                    acc2[r] = fmaf(FEXP2(a[r]*0.25f), rr, acc2[r]);
            }
        }
    }

    // full-wave butterfly (64 lanes): each wave owns its 4 rows entirely
    #pragma unroll
    for (int r = 0; r < 4; ++r) {
        float v = acc1[r];
        #pragma unroll
        for (int s = 1; s < 64; s <<= 1) v += __shfl_xor(v, s);
        acc1[r] = v;
        if (MODE==2 && !CB0) {
            float u = acc2[r];
            #pragma unroll
            for (int s = 1; s < 64; s <<= 1) u += __shfl_xor(u, s);
            acc2[r] = u;
        }
    }
    if (MODE==2 && CB0) {
        float u = sumRem;
        #pragma unroll
        for (int s = 1; s < 64; s <<= 1) u += __shfl_xor(u, s);
        sumRem = u;
    }

    if (lane == 0) {
        #pragma unroll
        for (int r = 0; r < 4; ++r) {
            const int gi = b*N_ + rowbase + r;
            if (MODE==0) {
                ratL[gi] = 1.0f / (1e-9f + acc1[r]);
                remL[gi] = 1.0f;
                remR[gi] = 1.0f;                 // n==m: rows double as col init
            } else if (MODE==1) {
                const float rr  = remR[gi];
                const float rat = rr / (1e-9f + acc1[r]);
                ratR[(size_t)lvl*BN + gi] = rat;
                remR[gi] = fmaxf(0.0f, rr - rat*acc1[r]);
            } else {
                const float s2  = CB0 ? sumRem : acc2[r];
                const float rl  = remL[gi];
                const float nl  = fmaxf(0.0f, rl - ratL[(size_t)lvl*BN + gi]*acc1[r]);
                remL[gi] = nl;
                ratL[(size_t)(lvl+1)*BN + gi] = nl / (1e-9f + s2);
            }
        }
    }
}

// level 9 (W == 1) col pass is rank-1: sumL = sum_i ratioL9[i]; ratioR9[j] = remR[j]/(1e-9+sumL)
__global__ __launch_bounds__(THREADS)
void ratr9_kernel(float* __restrict__ ws)
{
    float* remR  = ws + BN;
    float* ratL9 = ws + 2*BN  + (size_t)9*BN;
    float* ratR9 = ws + 12*BN + (size_t)9*BN;
    const int b = blockIdx.x, t = threadIdx.x;
    __shared__ float sred[4];
    float s = 0.f;
    for (int k = t; k < N_; k += THREADS) s += ratL9[b*N_ + k];
    #pragma unroll
    for (int d = 1; d < 64; d <<= 1) s += __shfl_xor(s, d);
    if ((t & 63) == 0) sred[t >> 6] = s;
    __syncthreads();
    const float inv = 1.0f / (1e-9f + (sred[0]+sred[1]+sred[2]+sred[3]));
    for (int k = t; k < N_; k += THREADS) ratR9[b*N_ + k] = remR[b*N_ + k] * inv;
}

// match_ij = sum_l W_l * ratioL_l[i] * ratioR_l[j]; out[b][j][i] = match_ij
// cost_b = sum_ij match_ij * sqrt(sqd_ij)
// ITILE=4 i's per thread so each broadcast LDS read serves 256 entries.
static constexpr int JCH = 32;

__global__ __launch_bounds__(256, 4)
void match_kernel(const float* __restrict__ xyz1, const float* __restrict__ xyz2,
                  const float* __restrict__ ws, float* __restrict__ out,
                  float c8, float invc8)
{
    __shared__ float4 pts[JCH];
    __shared__ __align__(16) float rrs[JCH][12];   // 10 levels padded to 12 (16B rows)
    __shared__ float cred[4];

    const float* ratL = ws + 2*BN;
    const float* ratR = ws + 12*BN;
    float* outCost  = out;
    float* outMatch = out + B_;

    const int wg = blockIdx.x;          // b(8) x ic(2) x jc(64)
    const int b  = wg >> 7;
    const int ic = (wg >> 6) & 1;
    const int jc = wg & 63;
    const int t  = threadIdx.x;
    const int jbase = jc * JCH;

    if (t < JCH) {
        const float* p = xyz2 + (size_t)(b*N_ + jbase + t)*3;
        pts[t] = make_float4(p[0], p[1], p[2], 0.f);
    }
    for (int k = t; k < 10*JCH; k += 256) {
        const int l = k >> 5, ji = k & 31;
        rrs[ji][l] = ratR[(size_t)l*BN + b*N_ + jbase + ji];
    }

    float bx[4], by[4], bz[4], bq[4], RL[4][10];
    #pragma unroll
    for (int k = 0; k < 4; ++k) {
        const int i = ic*1024 + k*256 + t;
        const float* q = xyz1 + (size_t)(b*N_ + i)*3;
        const float qx = q[0], qy = q[1], qz = q[2];
        bx[k] = -2.0f*c8*qx; by[k] = -2.0f*c8*qy; bz[k] = -2.0f*c8*qz;
        bq[k] = c8 * fmaf(qx,qx, fmaf(qy,qy, qz*qz));
        #pragma unroll
        for (int l = 0; l < 10; ++l) RL[k][l] = ratL[(size_t)l*BN + b*N_ + i];
    }
    __syncthreads();

    float cost = 0.f;
    const size_t ob0 = (size_t)b*N_*N_ + (size_t)jbase*N_ + (size_t)(ic*1024) + t;

    for (int jj = 0; jj < JCH; ++jj) {
        const float4 p  = pts[jj];
        const float4 rA = *(const float4*)&rrs[jj][0];   // levels 0..3
        const float4 rB = *(const float4*)&rrs[jj][4];   // levels 4..7
        const float4 rC = *(const float4*)&rrs[jj][8];   // levels 8,9
        const float cpp = c8 * fmaf(p.x,p.x, fmaf(p.y,p.y, p.z*p.z));
        float a[4], m[4], sd[4];
        #pragma unroll
        for (int k = 0; k < 4; ++k) {
            a[k]  = fmaf(bx[k],p.x, fmaf(by[k],p.y, fmaf(bz[k],p.z, cpp + bq[k])));
            sd[k] = sqrtf(a[k] * invc8);
            m[k]  = RL[k][9] * rC.y;               // level 9: W = 1
        }
        // levels 8..0, arg_{l-1} = 4*arg_l (monotone more negative); wave early-out
        #define DL(lv, rv) { _Pragma("unroll") \
            for (int k = 0; k < 4; ++k) { \
                m[k] = fmaf(FEXP2(a[k]) * RL[k][lv], rv, m[k]); a[k] *= 4.0f; } }
        #define ALIVE __any(fmaxf(fmaxf(a[0],a[1]), fmaxf(a[2],a[3])) >= -151.0f)
        DL(8, rC.x)
        if (ALIVE) { DL(7, rB.w)
         if (ALIVE) { DL(6, rB.z)
          if (ALIVE) { DL(5, rB.y)
           if (ALIVE) { DL(4, rB.x)
            if (ALIVE) { DL(3, rA.w)
             if (ALIVE) { DL(2, rA.z)
              if (ALIVE) { DL(1, rA.y)
               if (ALIVE) { DL(0, rA.x) } } } } } } } }
        #undef DL
        #undef ALIVE
        #pragma unroll
        for (int k = 0; k < 4; ++k) {
            __builtin_nontemporal_store(m[k], &outMatch[ob0 + (size_t)jj*N_ + k*256]);
            cost = fmaf(m[k], sd[k], cost);
        }
    }

    #pragma unroll
    for (int s = 1; s < 64; s <<= 1) cost += __shfl_xor(cost, s);
    const int wave = t >> 6, lane = t & 63;
    if (lane == 0) cred[wave] = cost;
    __syncthreads();
    if (t == 0) atomicAdd(outCost + b, cred[0]+cred[1]+cred[2]+cred[3]);
}

extern "C" void kernel_launch(void* const* d_in, const int* in_sizes, int n_in,
                              void* d_out, int out_size, void* d_ws, size_t ws_size,
                              hipStream_t stream) {
    const float* xyz1 = (const float*)d_in[0];
    const float* xyz2 = (const float*)d_in[1];
    float* out = (float*)d_out;
    float* ws  = (float*)d_ws;

    const double L2E = 1.4426950408889634;
    float c[10];
    for (int l = 0; l < 9; ++l) c[l] = (float)(-pow(4.0, 7 - l) * L2E);
    c[9] = 0.0f;

    dim3 grid(B_*WPC), blk(THREADS);
    // bootstrap: level 0 row pass (also inits remL/remR and zeroes cost)
    pass_kernel<0,false><<<grid, blk, 0, stream>>>(xyz1, xyz2, ws, out, c[0], -151.f, 0);
    for (int l = 0; l < 9; ++l) {
        pass_kernel<1,false><<<grid, blk, 0, stream>>>(xyz1, xyz2, ws, out, c[l], -151.f, l);
        if (l < 8)
            pass_kernel<2,false><<<grid, blk, 0, stream>>>(xyz1, xyz2, ws, out, c[l], -604.f, l);
        else
            pass_kernel<2,true><<<grid, blk, 0, stream>>>(xyz1, xyz2, ws, out, c[l], -151.f, l);
    }
    ratr9_kernel<<<dim3(B_), blk, 0, stream>>>(ws);
    match_kernel<<<dim3(B_*128), dim3(256), 0, stream>>>(xyz1, xyz2, ws, out, c[8], 1.0f/c[8]);
}